// Round 1
// baseline (784.241 us; speedup 1.0000x reference)
//
#include <hip/hip_runtime.h>
#include <hip/hip_bf16.h>

// Problem constants (from reference): N=4096 support, B=512 histograms.
#define NN 4096
#define BB 512
#define NB (NN * BB)

// eps/lamda arrive as 1-element arrays; Python ints may be int32/int64,
// floats would be float32. Heuristic: small positive int bits => integer,
// else reinterpret as float. (int64 little-endian low word == value for
// small ints; float32 1.0 = 0x3f800000 > 1e6.)
__device__ __forceinline__ float scal_val(const void* p) {
    int b = *(const int*)p;
    if (b >= 1 && b <= 1000000) return (float)b;
    return __int_as_float(b);
}

// ---------------------------------------------------------------------------
// Kernel A: elementwise precompute  f = exp(flog), g = f*flog
// flog = (lam/eps)*log(lam/(lam-u))
// ---------------------------------------------------------------------------
__global__ __launch_bounds__(256) void k_elem(const float* __restrict__ U,
                                              float* __restrict__ fbuf,
                                              float* __restrict__ gbuf,
                                              const void* epsp, const void* lamp) {
    float eps = scal_val(epsp), lam = scal_val(lamp);
    float r = lam / eps;
    int idx = (blockIdx.x * 256 + threadIdx.x) * 4;
    float4 u4 = *(const float4*)(U + idx);
    float u[4] = {u4.x, u4.y, u4.z, u4.w};
    float fo[4], go[4];
#pragma unroll
    for (int i = 0; i < 4; ++i) {
        float L = __logf(lam / (lam - u[i]));
        float fl = r * L;
        float f = __expf(fl);
        fo[i] = f;
        go[i] = f * fl;
    }
    *(float4*)(fbuf + idx) = make_float4(fo[0], fo[1], fo[2], fo[3]);
    *(float4*)(gbuf + idx) = make_float4(go[0], go[1], go[2], go[3]);
}

__device__ __forceinline__ void block_reduce_atomic(double v, double* red, int tid,
                                                    double* target) {
    __syncthreads();
    red[tid] = v;
    __syncthreads();
#pragma unroll
    for (int s = 128; s > 0; s >>= 1) {
        if (tid < s) red[tid] += red[tid + s];
        __syncthreads();
    }
    if (tid == 0) atomicAdd(target, red[0]);
}

// ---------------------------------------------------------------------------
// GEMM1 (fused dual): Y1 = K@f, Y2 = K@g  (64x64 tile, 4x4/thread)
// Epilogue: a = P/Y1 (stored), t1 += a*Y2, t2 += P*log(P/Y1), t3 += P
// ---------------------------------------------------------------------------
__global__ __launch_bounds__(256) void k_gemm1(const float* __restrict__ K,
                                               const float* __restrict__ fbuf,
                                               const float* __restrict__ gbuf,
                                               const float* __restrict__ P,
                                               float* __restrict__ abuf,
                                               double* __restrict__ acc) {
    __shared__ float As[64][17];
    __shared__ float Bsf[16][64];
    __shared__ float Bsg[16][64];
    __shared__ double red[256];

    const int tid = threadIdx.x;
    const int tx = tid & 15, ty = tid >> 4;
    const int j0 = blockIdx.x * 64;  // B dim
    const int i0 = blockIdx.y * 64;  // N dim (rows of K)

    float acc1[4][4] = {};
    float acc2[4][4] = {};

    const int ar = tid >> 2;         // 0..63  row in A-tile
    const int ac = (tid & 3) * 4;    // 0,4,8,12 col (k) in A-tile
    const int br = tid >> 4;         // 0..15  row (k) in B-tile
    const int bc = (tid & 15) * 4;   // 0..60  col (j) in B-tile

    for (int k0 = 0; k0 < NN; k0 += 16) {
        float4 av = *(const float4*)(K + (size_t)(i0 + ar) * NN + k0 + ac);
        float4 bf = *(const float4*)(fbuf + (size_t)(k0 + br) * BB + j0 + bc);
        float4 bg = *(const float4*)(gbuf + (size_t)(k0 + br) * BB + j0 + bc);
        __syncthreads();
        As[ar][ac + 0] = av.x;
        As[ar][ac + 1] = av.y;
        As[ar][ac + 2] = av.z;
        As[ar][ac + 3] = av.w;
        *(float4*)&Bsf[br][bc] = bf;
        *(float4*)&Bsg[br][bc] = bg;
        __syncthreads();
#pragma unroll
        for (int kk = 0; kk < 16; ++kk) {
            float a0 = As[ty * 4 + 0][kk];
            float a1 = As[ty * 4 + 1][kk];
            float a2 = As[ty * 4 + 2][kk];
            float a3 = As[ty * 4 + 3][kk];
            float4 vf = *(const float4*)&Bsf[kk][tx * 4];
            float4 vg = *(const float4*)&Bsg[kk][tx * 4];
            float aa[4] = {a0, a1, a2, a3};
            float bfv[4] = {vf.x, vf.y, vf.z, vf.w};
            float bgv[4] = {vg.x, vg.y, vg.z, vg.w};
#pragma unroll
            for (int i = 0; i < 4; ++i)
#pragma unroll
                for (int j = 0; j < 4; ++j) {
                    acc1[i][j] += aa[i] * bfv[j];
                    acc2[i][j] += aa[i] * bgv[j];
                }
        }
    }

    double t1 = 0.0, t2 = 0.0, t3 = 0.0;
#pragma unroll
    for (int i = 0; i < 4; ++i) {
        int gi = i0 + ty * 4 + i;
        float4 p4 = *(const float4*)(P + (size_t)gi * BB + j0 + tx * 4);
        float pv[4] = {p4.x, p4.y, p4.z, p4.w};
        float av[4];
#pragma unroll
        for (int j = 0; j < 4; ++j) {
            float y1 = acc1[i][j];
            float aij = pv[j] / y1;
            av[j] = aij;
            t1 += (double)(aij * acc2[i][j]);
            t2 += (double)(pv[j] * __logf(pv[j] / y1));
            t3 += (double)pv[j];
        }
        *(float4*)(abuf + (size_t)gi * BB + j0 + tx * 4) =
            make_float4(av[0], av[1], av[2], av[3]);
    }

    block_reduce_atomic(t1, red, tid, &acc[0]);
    block_reduce_atomic(t2, red, tid, &acc[1]);
    block_reduce_atomic(t3, red, tid, &acc[2]);
}

// ---------------------------------------------------------------------------
// GEMM2: S = K^T @ a (64x64 tile), consumed in-register:
//   kl -= f*(1+L)*S   with f,L recomputed from U on the fly.
// ---------------------------------------------------------------------------
__global__ __launch_bounds__(256) void k_gemm2(const float* __restrict__ K,
                                               const float* __restrict__ abuf,
                                               const float* __restrict__ U,
                                               const void* epsp, const void* lamp,
                                               double* __restrict__ acc) {
    __shared__ float As2[16][64];
    __shared__ float Bs2[16][64];
    __shared__ double red[256];

    const float eps = scal_val(epsp), lam = scal_val(lamp);
    const int tid = threadIdx.x;
    const int tx = tid & 15, ty = tid >> 4;
    const int j0 = blockIdx.x * 64;  // B dim
    const int i0 = blockIdx.y * 64;  // N dim (cols of K = rows of S)

    float s[4][4] = {};

    const int br = tid >> 4;        // 0..15 (k)
    const int bc = (tid & 15) * 4;  // 0..60

    for (int k0 = 0; k0 < NN; k0 += 16) {
        float4 ka = *(const float4*)(K + (size_t)(k0 + br) * NN + i0 + bc);
        float4 aa = *(const float4*)(abuf + (size_t)(k0 + br) * BB + j0 + bc);
        __syncthreads();
        *(float4*)&As2[br][bc] = ka;
        *(float4*)&Bs2[br][bc] = aa;
        __syncthreads();
#pragma unroll
        for (int kk = 0; kk < 16; ++kk) {
            float4 va = *(const float4*)&As2[kk][ty * 4];
            float4 vb = *(const float4*)&Bs2[kk][tx * 4];
            float aa4[4] = {va.x, va.y, va.z, va.w};
            float bb4[4] = {vb.x, vb.y, vb.z, vb.w};
#pragma unroll
            for (int i = 0; i < 4; ++i)
#pragma unroll
                for (int j = 0; j < 4; ++j) s[i][j] += aa4[i] * bb4[j];
        }
    }

    const float r = lam / eps;
    double klp = 0.0;
#pragma unroll
    for (int i = 0; i < 4; ++i) {
        int gi = i0 + ty * 4 + i;
        float4 u4 = *(const float4*)(U + (size_t)gi * BB + j0 + tx * 4);
        float uu[4] = {u4.x, u4.y, u4.z, u4.w};
#pragma unroll
        for (int j = 0; j < 4; ++j) {
            float L = __logf(lam / (lam - uu[j]));
            float fv = __expf(r * L);
            klp -= (double)(fv * (1.0f + L) * s[i][j]);
        }
    }

    block_reduce_atomic(klp, red, tid, &acc[3]);
}

// ---------------------------------------------------------------------------
// Final: out = eps*(t1+t2-t3) + lam*kl
// ---------------------------------------------------------------------------
__global__ void k_final(const double* __restrict__ acc, const void* epsp,
                        const void* lamp, float* __restrict__ out) {
    float eps = scal_val(epsp), lam = scal_val(lamp);
    double v = (double)eps * (acc[0] + acc[1] - acc[2]) + (double)lam * acc[3];
    out[0] = (float)v;
}

extern "C" void kernel_launch(void* const* d_in, const int* in_sizes, int n_in,
                              void* d_out, int out_size, void* d_ws, size_t ws_size,
                              hipStream_t stream) {
    const float* U = (const float*)d_in[0];
    const float* P = (const float*)d_in[1];
    const float* K = (const float*)d_in[2];
    const void* epsp = d_in[3];
    const void* lamp = d_in[4];

    // Workspace layout: [0..32) four double accumulators; then f, g, a (f32 NxB).
    double* acc = (double*)d_ws;
    float* fbuf = (float*)((char*)d_ws + 256);
    float* gbuf = fbuf + NB;
    float* abuf = gbuf + NB;

    hipMemsetAsync(acc, 0, 4 * sizeof(double), stream);

    k_elem<<<NB / 1024, 256, 0, stream>>>(U, fbuf, gbuf, epsp, lamp);

    dim3 g1(BB / 64, NN / 64);
    k_gemm1<<<g1, 256, 0, stream>>>(K, fbuf, gbuf, P, abuf, acc);
    k_gemm2<<<g1, 256, 0, stream>>>(K, abuf, U, epsp, lamp, acc);

    k_final<<<1, 1, 0, stream>>>(acc, epsp, lamp, (float*)d_out);
}

// Round 2
// 341.905 us; speedup vs baseline: 2.2937x; 2.2937x over previous
//
#include <hip/hip_runtime.h>
#include <hip/hip_bf16.h>

#define NN 4096
#define BB 512

typedef __attribute__((ext_vector_type(8))) short short8;   // 8 bf16 (4 VGPRs)
typedef __attribute__((ext_vector_type(4))) float f32x4;    // MFMA C/D frag
typedef unsigned short ushort;
typedef __attribute__((ext_vector_type(4))) ushort ushort4v;

__device__ __forceinline__ float scal_val(const void* p) {
    int b = *(const int*)p;
    if (b >= 1 && b <= 1000000) return (float)b;
    return __int_as_float(b);
}

// f32 -> bf16 bits, round-to-nearest-even (inputs are finite positive here)
__device__ __forceinline__ ushort f2bf(float x) {
    unsigned u = __float_as_uint(x);
    u += 0x7fffu + ((u >> 16) & 1u);
    return (ushort)(u >> 16);
}

__device__ __forceinline__ void gload16(const void* g, void* l) {
    __builtin_amdgcn_global_load_lds(
        (const __attribute__((address_space(1))) unsigned int*)g,
        (__attribute__((address_space(3))) unsigned int*)l, 16, 0, 0);
}

__device__ __forceinline__ double wave_sum(double v) {
#pragma unroll
    for (int s = 32; s > 0; s >>= 1) v += __shfl_down(v, s, 64);
    return v;
}

// ---------------------------------------------------------------------------
// K (fp32 NxN) -> Kb (bf16, row-major) and KTb (bf16, transposed row-major)
// ---------------------------------------------------------------------------
__global__ __launch_bounds__(256) void k_prep_K(const float* __restrict__ K,
                                                ushort* __restrict__ Kb,
                                                ushort* __restrict__ KTb) {
    __shared__ float tile[64][65];
    const int t = threadIdx.x;
    const int tx = t & 15, ty = t >> 4;
    const int c0 = blockIdx.x * 64, r0 = blockIdx.y * 64;
#pragma unroll
    for (int it = 0; it < 4; ++it) {
        int row = ty + it * 16;
        float4 v = *(const float4*)&K[(size_t)(r0 + row) * NN + c0 + tx * 4];
        ushort4v o = {f2bf(v.x), f2bf(v.y), f2bf(v.z), f2bf(v.w)};
        *(ushort4v*)&Kb[(size_t)(r0 + row) * NN + c0 + tx * 4] = o;
        tile[row][tx * 4 + 0] = v.x;
        tile[row][tx * 4 + 1] = v.y;
        tile[row][tx * 4 + 2] = v.z;
        tile[row][tx * 4 + 3] = v.w;
    }
    __syncthreads();
#pragma unroll
    for (int it = 0; it < 4; ++it) {
        int row = ty + it * 16;  // col within tile -> KT row (c0+row)
        ushort4v o = {f2bf(tile[tx * 4 + 0][row]), f2bf(tile[tx * 4 + 1][row]),
                      f2bf(tile[tx * 4 + 2][row]), f2bf(tile[tx * 4 + 3][row])};
        *(ushort4v*)&KTb[(size_t)(c0 + row) * NN + r0 + tx * 4] = o;
    }
}

// ---------------------------------------------------------------------------
// U (fp32 NxB) -> fT, gT (bf16, TRANSPOSED: [j][k] row-major, BxN)
// f = (lam/(lam-u))^(lam/eps) = exp(flog), g = f*flog
// ---------------------------------------------------------------------------
__global__ __launch_bounds__(256) void k_prep_fg(const float* __restrict__ U,
                                                 ushort* __restrict__ fT,
                                                 ushort* __restrict__ gT,
                                                 const void* epsp, const void* lamp) {
    __shared__ float tf[64][65];
    __shared__ float tg[64][65];
    const float eps = scal_val(epsp), lam = scal_val(lamp);
    const float rr = lam / eps;
    const int t = threadIdx.x;
    const int tx = t & 15, ty = t >> 4;
    const int c0 = blockIdx.x * 64;  // U col tile (j)
    const int r0 = blockIdx.y * 64;  // U row tile (k)
#pragma unroll
    for (int it = 0; it < 4; ++it) {
        int row = ty + it * 16;
        float4 v = *(const float4*)&U[(size_t)(r0 + row) * BB + c0 + tx * 4];
        float uu[4] = {v.x, v.y, v.z, v.w};
#pragma unroll
        for (int k = 0; k < 4; ++k) {
            float L = __logf(lam / (lam - uu[k]));
            float fl = rr * L;
            float fv = __expf(fl);
            tf[row][tx * 4 + k] = fv;
            tg[row][tx * 4 + k] = fv * fl;
        }
    }
    __syncthreads();
#pragma unroll
    for (int it = 0; it < 4; ++it) {
        int row = ty + it * 16;  // col within tile -> output row (c0+row)
        ushort4v of = {f2bf(tf[tx * 4 + 0][row]), f2bf(tf[tx * 4 + 1][row]),
                       f2bf(tf[tx * 4 + 2][row]), f2bf(tf[tx * 4 + 3][row])};
        ushort4v og = {f2bf(tg[tx * 4 + 0][row]), f2bf(tg[tx * 4 + 1][row]),
                       f2bf(tg[tx * 4 + 2][row]), f2bf(tg[tx * 4 + 3][row])};
        *(ushort4v*)&fT[(size_t)(c0 + row) * NN + r0 + tx * 4] = of;
        *(ushort4v*)&gT[(size_t)(c0 + row) * NN + r0 + tx * 4] = og;
    }
}

// ---------------------------------------------------------------------------
// GEMM1 (MFMA, dual): Y1 = Kb@f, Y2 = Kb@g.  128(M)x64(j) tile, BK=64, dbuf.
// Epilogue: a=P/Y1 -> aT (bf16 [j][i]); t1 += a*Y2, t2 += P*log(P/Y1), t3 += P
// ---------------------------------------------------------------------------
__global__ __launch_bounds__(256) void k_gemm1(const ushort* __restrict__ Kb,
                                               const ushort* __restrict__ fT,
                                               const ushort* __restrict__ gT,
                                               const float* __restrict__ P,
                                               ushort* __restrict__ aT,
                                               double* __restrict__ acc) {
    __shared__ __align__(16) ushort As[2][128 * 64];
    __shared__ __align__(16) ushort Bf[2][64 * 64];
    __shared__ __align__(16) ushort Bg[2][64 * 64];

    const int tid = threadIdx.x;
    const int lane = tid & 63;
    const int w = tid >> 6;
    const int wm = w & 1, wn = w >> 1;
    const int bid = blockIdx.x;
    const int i0 = (bid & 31) * 128;   // same-i blocks share XCD (bid%8==i%8)
    const int j0 = (bid >> 5) * 64;
    const int quad = lane >> 4;
    const int l15 = lane & 15;

    f32x4 zero = {0.f, 0.f, 0.f, 0.f};
    f32x4 accf[4][2], accg[4][2];
#pragma unroll
    for (int mt = 0; mt < 4; ++mt)
#pragma unroll
        for (int nt = 0; nt < 2; ++nt) { accf[mt][nt] = zero; accg[mt][nt] = zero; }

    const int lr8 = lane >> 3, lc8 = (lane & 7) * 8;

    auto stage = [&](int k0, int b) {
        // A-tile: wave w stages rows [w*32, w*32+32)
        const ushort* ga = Kb + (size_t)(i0 + w * 32 + lr8) * NN + k0 + lc8;
        ushort* la = &As[b][(w * 32) * 64];
#pragma unroll
        for (int it = 0; it < 4; ++it)
            gload16(ga + (size_t)it * 8 * NN, la + it * 8 * 64);
        // B-tiles: wave w stages rows [w*16, w*16+16)
        const ushort* gf = fT + (size_t)(j0 + w * 16 + lr8) * NN + k0 + lc8;
        const ushort* gg = gT + (size_t)(j0 + w * 16 + lr8) * NN + k0 + lc8;
#pragma unroll
        for (int it = 0; it < 2; ++it) {
            gload16(gf + (size_t)it * 8 * NN, &Bf[b][(w * 16 + it * 8) * 64]);
            gload16(gg + (size_t)it * 8 * NN, &Bg[b][(w * 16 + it * 8) * 64]);
        }
    };

    stage(0, 0);
    __syncthreads();
    for (int step = 0; step < NN / 64; ++step) {
        const int cur = step & 1;
        if (step < NN / 64 - 1) stage((step + 1) * 64, cur ^ 1);
#pragma unroll
        for (int ks = 0; ks < 2; ++ks) {
            short8 af[4];
#pragma unroll
            for (int mt = 0; mt < 4; ++mt)
                af[mt] = *(const short8*)&As[cur][(wm * 64 + mt * 16 + l15) * 64 + ks * 32 + quad * 8];
            short8 bfv[2], bgv[2];
#pragma unroll
            for (int nt = 0; nt < 2; ++nt) {
                bfv[nt] = *(const short8*)&Bf[cur][(wn * 32 + nt * 16 + l15) * 64 + ks * 32 + quad * 8];
                bgv[nt] = *(const short8*)&Bg[cur][(wn * 32 + nt * 16 + l15) * 64 + ks * 32 + quad * 8];
            }
#pragma unroll
            for (int mt = 0; mt < 4; ++mt)
#pragma unroll
                for (int nt = 0; nt < 2; ++nt) {
                    accf[mt][nt] = __builtin_amdgcn_mfma_f32_16x16x32_bf16(
                        af[mt], bfv[nt], accf[mt][nt], 0, 0, 0);
                    accg[mt][nt] = __builtin_amdgcn_mfma_f32_16x16x32_bf16(
                        af[mt], bgv[nt], accg[mt][nt], 0, 0, 0);
                }
        }
        __syncthreads();
    }

    // Epilogue. C/D layout: col = lane&15, row = quad*4 + reg.
    double t1 = 0.0, t2 = 0.0, t3 = 0.0;
#pragma unroll
    for (int mt = 0; mt < 4; ++mt)
#pragma unroll
        for (int nt = 0; nt < 2; ++nt) {
            const int ib = i0 + wm * 64 + mt * 16 + quad * 4;
            const int j = j0 + wn * 32 + nt * 16 + l15;
            ushort a0, a1, a2, a3;
            float y1, y2, p, aij;
            y1 = accf[mt][nt][0]; y2 = accg[mt][nt][0];
            p = P[(size_t)(ib + 0) * BB + j]; aij = p / y1;
            t1 += (double)(aij * y2); t2 += (double)(p * __logf(aij)); t3 += (double)p; a0 = f2bf(aij);
            y1 = accf[mt][nt][1]; y2 = accg[mt][nt][1];
            p = P[(size_t)(ib + 1) * BB + j]; aij = p / y1;
            t1 += (double)(aij * y2); t2 += (double)(p * __logf(aij)); t3 += (double)p; a1 = f2bf(aij);
            y1 = accf[mt][nt][2]; y2 = accg[mt][nt][2];
            p = P[(size_t)(ib + 2) * BB + j]; aij = p / y1;
            t1 += (double)(aij * y2); t2 += (double)(p * __logf(aij)); t3 += (double)p; a2 = f2bf(aij);
            y1 = accf[mt][nt][3]; y2 = accg[mt][nt][3];
            p = P[(size_t)(ib + 3) * BB + j]; aij = p / y1;
            t1 += (double)(aij * y2); t2 += (double)(p * __logf(aij)); t3 += (double)p; a3 = f2bf(aij);
            ushort4v ov = {a0, a1, a2, a3};
            *(ushort4v*)&aT[(size_t)j * NN + ib] = ov;
        }

    t1 = wave_sum(t1); t2 = wave_sum(t2); t3 = wave_sum(t3);
    if (lane == 0) {
        atomicAdd(&acc[0], t1);
        atomicAdd(&acc[1], t2);
        atomicAdd(&acc[2], t3);
    }
}

// ---------------------------------------------------------------------------
// GEMM2 (MFMA): S = KTb @ a  (A=KTb row-major, B=aT [j][k]).  kl -= f*(1+L)*S
// ---------------------------------------------------------------------------
__global__ __launch_bounds__(256) void k_gemm2(const ushort* __restrict__ KTb,
                                               const ushort* __restrict__ aT,
                                               const float* __restrict__ U,
                                               const void* epsp, const void* lamp,
                                               double* __restrict__ acc) {
    __shared__ __align__(16) ushort As[2][128 * 64];
    __shared__ __align__(16) ushort Bs[2][64 * 64];

    const float eps = scal_val(epsp), lam = scal_val(lamp);
    const float rr = lam / eps;
    const int tid = threadIdx.x;
    const int lane = tid & 63;
    const int w = tid >> 6;
    const int wm = w & 1, wn = w >> 1;
    const int bid = blockIdx.x;
    const int i0 = (bid & 31) * 128;
    const int j0 = (bid >> 5) * 64;
    const int quad = lane >> 4;
    const int l15 = lane & 15;

    f32x4 zero = {0.f, 0.f, 0.f, 0.f};
    f32x4 accs[4][2];
#pragma unroll
    for (int mt = 0; mt < 4; ++mt)
#pragma unroll
        for (int nt = 0; nt < 2; ++nt) accs[mt][nt] = zero;

    const int lr8 = lane >> 3, lc8 = (lane & 7) * 8;

    auto stage = [&](int k0, int b) {
        const ushort* ga = KTb + (size_t)(i0 + w * 32 + lr8) * NN + k0 + lc8;
        ushort* la = &As[b][(w * 32) * 64];
#pragma unroll
        for (int it = 0; it < 4; ++it)
            gload16(ga + (size_t)it * 8 * NN, la + it * 8 * 64);
        const ushort* gb = aT + (size_t)(j0 + w * 16 + lr8) * NN + k0 + lc8;
#pragma unroll
        for (int it = 0; it < 2; ++it)
            gload16(gb + (size_t)it * 8 * NN, &Bs[b][(w * 16 + it * 8) * 64]);
    };

    stage(0, 0);
    __syncthreads();
    for (int step = 0; step < NN / 64; ++step) {
        const int cur = step & 1;
        if (step < NN / 64 - 1) stage((step + 1) * 64, cur ^ 1);
#pragma unroll
        for (int ks = 0; ks < 2; ++ks) {
            short8 af[4];
#pragma unroll
            for (int mt = 0; mt < 4; ++mt)
                af[mt] = *(const short8*)&As[cur][(wm * 64 + mt * 16 + l15) * 64 + ks * 32 + quad * 8];
            short8 bv[2];
#pragma unroll
            for (int nt = 0; nt < 2; ++nt)
                bv[nt] = *(const short8*)&Bs[cur][(wn * 32 + nt * 16 + l15) * 64 + ks * 32 + quad * 8];
#pragma unroll
            for (int mt = 0; mt < 4; ++mt)
#pragma unroll
                for (int nt = 0; nt < 2; ++nt)
                    accs[mt][nt] = __builtin_amdgcn_mfma_f32_16x16x32_bf16(
                        af[mt], bv[nt], accs[mt][nt], 0, 0, 0);
        }
        __syncthreads();
    }

    double klp = 0.0;
#pragma unroll
    for (int mt = 0; mt < 4; ++mt)
#pragma unroll
        for (int nt = 0; nt < 2; ++nt) {
            const int ib = i0 + wm * 64 + mt * 16 + quad * 4;
            const int j = j0 + wn * 32 + nt * 16 + l15;
#pragma unroll
            for (int r = 0; r < 4; ++r) {
                float s = accs[mt][nt][r];
                float u = U[(size_t)(ib + r) * BB + j];
                float L = __logf(lam / (lam - u));
                float fv = __expf(rr * L);
                klp -= (double)(fv * (1.0f + L) * s);
            }
        }

    klp = wave_sum(klp);
    if (lane == 0) atomicAdd(&acc[3], klp);
}

__global__ void k_final(const double* __restrict__ acc, const void* epsp,
                        const void* lamp, float* __restrict__ out) {
    float eps = scal_val(epsp), lam = scal_val(lamp);
    double v = (double)eps * (acc[0] + acc[1] - acc[2]) + (double)lam * acc[3];
    out[0] = (float)v;
}

extern "C" void kernel_launch(void* const* d_in, const int* in_sizes, int n_in,
                              void* d_out, int out_size, void* d_ws, size_t ws_size,
                              hipStream_t stream) {
    const float* U = (const float*)d_in[0];
    const float* P = (const float*)d_in[1];
    const float* K = (const float*)d_in[2];
    const void* epsp = d_in[3];
    const void* lamp = d_in[4];

    // Workspace: acc (256 B) | Kb 32MB | KTb 32MB | fT 4MB | gT 4MB | aT 4MB
    double* acc = (double*)d_ws;
    char* base = (char*)d_ws + 256;
    ushort* Kb  = (ushort*)base;
    ushort* KTb = (ushort*)(base + ((size_t)32 << 20));
    ushort* fT  = (ushort*)(base + ((size_t)64 << 20));
    ushort* gT  = (ushort*)(base + ((size_t)68 << 20));
    ushort* aT  = (ushort*)(base + ((size_t)72 << 20));

    hipMemsetAsync(acc, 0, 4 * sizeof(double), stream);

    k_prep_K<<<dim3(64, 64), 256, 0, stream>>>(K, Kb, KTb);
    k_prep_fg<<<dim3(8, 64), 256, 0, stream>>>(U, fT, gT, epsp, lamp);
    k_gemm1<<<256, 256, 0, stream>>>(Kb, fT, gT, P, aT, acc);
    k_gemm2<<<256, 256, 0, stream>>>(KTb, aT, U, epsp, lamp, acc);
    k_final<<<1, 1, 0, stream>>>(acc, epsp, lamp, (float*)d_out);
}

// Round 3
// 318.858 us; speedup vs baseline: 2.4595x; 1.0723x over previous
//
#include <hip/hip_runtime.h>
#include <hip/hip_bf16.h>

#define NN 4096
#define BB 512

typedef __attribute__((ext_vector_type(8))) short short8;   // 8 bf16 (4 VGPRs)
typedef __attribute__((ext_vector_type(4))) float f32x4;    // MFMA C/D frag
typedef unsigned short ushort;
typedef __attribute__((ext_vector_type(4))) ushort ushort4v;

__device__ __forceinline__ float scal_val(const void* p) {
    int b = *(const int*)p;
    if (b >= 1 && b <= 1000000) return (float)b;
    return __int_as_float(b);
}

// f32 -> bf16 bits, round-to-nearest-even (inputs are finite positive here)
__device__ __forceinline__ ushort f2bf(float x) {
    unsigned u = __float_as_uint(x);
    u += 0x7fffu + ((u >> 16) & 1u);
    return (ushort)(u >> 16);
}

__device__ __forceinline__ void gload16(const void* g, void* l) {
    __builtin_amdgcn_global_load_lds(
        (const __attribute__((address_space(1))) unsigned int*)g,
        (__attribute__((address_space(3))) unsigned int*)l, 16, 0, 0);
}

__device__ __forceinline__ double wave_sum(double v) {
#pragma unroll
    for (int s = 32; s > 0; s >>= 1) v += __shfl_down(v, s, 64);
    return v;
}

// ---------------------------------------------------------------------------
// K (fp32 NxN) -> Kb (bf16, row-major) and KTb (bf16, transposed row-major)
// ---------------------------------------------------------------------------
__global__ __launch_bounds__(256) void k_prep_K(const float* __restrict__ K,
                                                ushort* __restrict__ Kb,
                                                ushort* __restrict__ KTb) {
    __shared__ float tile[64][65];
    const int t = threadIdx.x;
    const int tx = t & 15, ty = t >> 4;
    const int c0 = blockIdx.x * 64, r0 = blockIdx.y * 64;
#pragma unroll
    for (int it = 0; it < 4; ++it) {
        int row = ty + it * 16;
        float4 v = *(const float4*)&K[(size_t)(r0 + row) * NN + c0 + tx * 4];
        ushort4v o = {f2bf(v.x), f2bf(v.y), f2bf(v.z), f2bf(v.w)};
        *(ushort4v*)&Kb[(size_t)(r0 + row) * NN + c0 + tx * 4] = o;
        tile[row][tx * 4 + 0] = v.x;
        tile[row][tx * 4 + 1] = v.y;
        tile[row][tx * 4 + 2] = v.z;
        tile[row][tx * 4 + 3] = v.w;
    }
    __syncthreads();
#pragma unroll
    for (int it = 0; it < 4; ++it) {
        int row = ty + it * 16;  // col within tile -> KT row (c0+row)
        ushort4v o = {f2bf(tile[tx * 4 + 0][row]), f2bf(tile[tx * 4 + 1][row]),
                      f2bf(tile[tx * 4 + 2][row]), f2bf(tile[tx * 4 + 3][row])};
        *(ushort4v*)&KTb[(size_t)(c0 + row) * NN + r0 + tx * 4] = o;
    }
}

// ---------------------------------------------------------------------------
// U (fp32 NxB) -> fT, gT (bf16, TRANSPOSED: [j][k] row-major, BxN)
// ---------------------------------------------------------------------------
__global__ __launch_bounds__(256) void k_prep_fg(const float* __restrict__ U,
                                                 ushort* __restrict__ fT,
                                                 ushort* __restrict__ gT,
                                                 const void* epsp, const void* lamp) {
    __shared__ float tf[64][65];
    __shared__ float tg[64][65];
    const float eps = scal_val(epsp), lam = scal_val(lamp);
    const float rr = lam / eps;
    const int t = threadIdx.x;
    const int tx = t & 15, ty = t >> 4;
    const int c0 = blockIdx.x * 64;  // U col tile (j)
    const int r0 = blockIdx.y * 64;  // U row tile (k)
#pragma unroll
    for (int it = 0; it < 4; ++it) {
        int row = ty + it * 16;
        float4 v = *(const float4*)&U[(size_t)(r0 + row) * BB + c0 + tx * 4];
        float uu[4] = {v.x, v.y, v.z, v.w};
#pragma unroll
        for (int k = 0; k < 4; ++k) {
            float L = __logf(lam / (lam - uu[k]));
            float fl = rr * L;
            float fv = __expf(fl);
            tf[row][tx * 4 + k] = fv;
            tg[row][tx * 4 + k] = fv * fl;
        }
    }
    __syncthreads();
#pragma unroll
    for (int it = 0; it < 4; ++it) {
        int row = ty + it * 16;
        ushort4v of = {f2bf(tf[tx * 4 + 0][row]), f2bf(tf[tx * 4 + 1][row]),
                       f2bf(tf[tx * 4 + 2][row]), f2bf(tf[tx * 4 + 3][row])};
        ushort4v og = {f2bf(tg[tx * 4 + 0][row]), f2bf(tg[tx * 4 + 1][row]),
                       f2bf(tg[tx * 4 + 2][row]), f2bf(tg[tx * 4 + 3][row])};
        *(ushort4v*)&fT[(size_t)(c0 + row) * NN + r0 + tx * 4] = of;
        *(ushort4v*)&gT[(size_t)(c0 + row) * NN + r0 + tx * 4] = og;
    }
}

// ---------------------------------------------------------------------------
// GEMM1 (MFMA, dual, K-split 2): partial Y1 = Kb@f, Y2 = Kb@g over K-half.
// Tile 128(M)x64(j), BK=64, dbuf, XOR-swizzled LDS.  Grid 512 (2 blocks/CU).
// ---------------------------------------------------------------------------
__global__ __launch_bounds__(256) void k_gemm1(const ushort* __restrict__ Kb,
                                               const ushort* __restrict__ fT,
                                               const ushort* __restrict__ gT,
                                               float* __restrict__ Y1p,
                                               float* __restrict__ Y2p) {
    __shared__ __align__(16) ushort As[2][128 * 64];
    __shared__ __align__(16) ushort Bf[2][64 * 64];
    __shared__ __align__(16) ushort Bg[2][64 * 64];

    const int tid = threadIdx.x;
    const int lane = tid & 63;
    const int w = tid >> 6;
    const int wm = w & 1, wn = w >> 1;
    const int bid = blockIdx.x;
    const int kh = bid & 1;                  // K-half
    const int i0 = ((bid >> 1) & 31) * 128;  // M panel
    const int j0 = (bid >> 6) * 64;          // j panel
    const int quad = lane >> 4;
    const int l15 = lane & 15;
    const int h7 = l15 & 7;

    f32x4 zero = {0.f, 0.f, 0.f, 0.f};
    f32x4 accf[4][2], accg[4][2];
#pragma unroll
    for (int mt = 0; mt < 4; ++mt)
#pragma unroll
        for (int nt = 0; nt < 2; ++nt) { accf[mt][nt] = zero; accg[mt][nt] = zero; }

    const int lr = lane >> 3;                 // 0..7 row-within-slab
    const int lc = ((lane & 7) ^ lr) * 8;     // XOR-swizzled fetch chunk

    auto stage = [&](int k0, int b) {
        const ushort* ga = Kb + (size_t)(i0 + w * 32 + lr) * NN + k0 + lc;
        ushort* la = &As[b][(w * 32) * 64];
#pragma unroll
        for (int it = 0; it < 4; ++it)
            gload16(ga + (size_t)it * 8 * NN, la + it * 8 * 64);
        const ushort* gf = fT + (size_t)(j0 + w * 16 + lr) * NN + k0 + lc;
        const ushort* gg = gT + (size_t)(j0 + w * 16 + lr) * NN + k0 + lc;
#pragma unroll
        for (int it = 0; it < 2; ++it) {
            gload16(gf + (size_t)it * 8 * NN, &Bf[b][(w * 16 + it * 8) * 64]);
            gload16(gg + (size_t)it * 8 * NN, &Bg[b][(w * 16 + it * 8) * 64]);
        }
    };

    const int kbase = kh * (NN / 2);
    stage(kbase, 0);
    __syncthreads();
    for (int step = 0; step < NN / 128; ++step) {   // 32 steps of BK=64
        const int cur = step & 1;
        if (step < NN / 128 - 1) stage(kbase + (step + 1) * 64, cur ^ 1);
#pragma unroll
        for (int ks = 0; ks < 2; ++ks) {
            const int ch = ((ks * 4 + quad) ^ h7) * 8;   // swizzled read chunk
            short8 af[4];
#pragma unroll
            for (int mt = 0; mt < 4; ++mt)
                af[mt] = *(const short8*)&As[cur][(wm * 64 + mt * 16 + l15) * 64 + ch];
            short8 bfv[2], bgv[2];
#pragma unroll
            for (int nt = 0; nt < 2; ++nt) {
                bfv[nt] = *(const short8*)&Bf[cur][(wn * 32 + nt * 16 + l15) * 64 + ch];
                bgv[nt] = *(const short8*)&Bg[cur][(wn * 32 + nt * 16 + l15) * 64 + ch];
            }
#pragma unroll
            for (int mt = 0; mt < 4; ++mt)
#pragma unroll
                for (int nt = 0; nt < 2; ++nt) {
                    accf[mt][nt] = __builtin_amdgcn_mfma_f32_16x16x32_bf16(
                        af[mt], bfv[nt], accf[mt][nt], 0, 0, 0);
                    accg[mt][nt] = __builtin_amdgcn_mfma_f32_16x16x32_bf16(
                        af[mt], bgv[nt], accg[mt][nt], 0, 0, 0);
                }
        }
        __syncthreads();
    }

    // Store fp32 partials [kh][i][j].  C/D layout: col=lane&15, row=quad*4+reg.
    float* o1 = Y1p + (size_t)kh * NN * BB;
    float* o2 = Y2p + (size_t)kh * NN * BB;
#pragma unroll
    for (int mt = 0; mt < 4; ++mt)
#pragma unroll
        for (int nt = 0; nt < 2; ++nt) {
            const int ib = i0 + wm * 64 + mt * 16 + quad * 4;
            const int j = j0 + wn * 32 + nt * 16 + l15;
#pragma unroll
            for (int r = 0; r < 4; ++r) {
                o1[(size_t)(ib + r) * BB + j] = accf[mt][nt][r];
                o2[(size_t)(ib + r) * BB + j] = accg[mt][nt][r];
            }
        }
}

// ---------------------------------------------------------------------------
// Epilogue: Y = sum of halves; a = P/Y1; t1 += a*Y2, t2 += P*log(a), t3 += P;
// aT (bf16, [j][i]) via LDS transpose.
// ---------------------------------------------------------------------------
__global__ __launch_bounds__(256) void k_epi(const float* __restrict__ Y1p,
                                             const float* __restrict__ Y2p,
                                             const float* __restrict__ P,
                                             ushort* __restrict__ aT,
                                             double* __restrict__ acc) {
    __shared__ float ta[64][65];
    const int t = threadIdx.x;
    const int lane = t & 63;
    const int tx = t & 15, ty = t >> 4;
    const int j0 = blockIdx.x * 64;
    const int i0 = blockIdx.y * 64;
    const size_t H = (size_t)NN * BB;

    double t1 = 0.0, t2 = 0.0, t3 = 0.0;
#pragma unroll
    for (int it = 0; it < 4; ++it) {
        int row = ty + it * 16;
        size_t off = (size_t)(i0 + row) * BB + j0 + tx * 4;
        float4 a1 = *(const float4*)(Y1p + off);
        float4 b1 = *(const float4*)(Y1p + H + off);
        float4 a2 = *(const float4*)(Y2p + off);
        float4 b2 = *(const float4*)(Y2p + H + off);
        float4 p4 = *(const float4*)(P + off);
        float y1[4] = {a1.x + b1.x, a1.y + b1.y, a1.z + b1.z, a1.w + b1.w};
        float y2[4] = {a2.x + b2.x, a2.y + b2.y, a2.z + b2.z, a2.w + b2.w};
        float pv[4] = {p4.x, p4.y, p4.z, p4.w};
#pragma unroll
        for (int e = 0; e < 4; ++e) {
            float aij = pv[e] / y1[e];
            t1 += (double)(aij * y2[e]);
            t2 += (double)(pv[e] * __logf(aij));
            t3 += (double)pv[e];
            ta[row][tx * 4 + e] = aij;
        }
    }
    __syncthreads();
#pragma unroll
    for (int it = 0; it < 4; ++it) {
        int row = ty + it * 16;  // col within tile -> aT row (j0+row)
        ushort4v o = {f2bf(ta[tx * 4 + 0][row]), f2bf(ta[tx * 4 + 1][row]),
                      f2bf(ta[tx * 4 + 2][row]), f2bf(ta[tx * 4 + 3][row])};
        *(ushort4v*)&aT[(size_t)(j0 + row) * NN + i0 + tx * 4] = o;
    }

    t1 = wave_sum(t1); t2 = wave_sum(t2); t3 = wave_sum(t3);
    if (lane == 0) {
        atomicAdd(&acc[0], t1);
        atomicAdd(&acc[1], t2);
        atomicAdd(&acc[2], t3);
    }
}

// ---------------------------------------------------------------------------
// GEMM2 (MFMA, K-split 2): partial S = KTb @ a; kl -= f*(1+L)*S  (linear in S,
// so each K-half reduces its own partial straight into acc[3]).
// ---------------------------------------------------------------------------
__global__ __launch_bounds__(256) void k_gemm2(const ushort* __restrict__ KTb,
                                               const ushort* __restrict__ aT,
                                               const float* __restrict__ U,
                                               const void* epsp, const void* lamp,
                                               double* __restrict__ acc) {
    __shared__ __align__(16) ushort As[2][128 * 64];
    __shared__ __align__(16) ushort Bs[2][64 * 64];

    const float eps = scal_val(epsp), lam = scal_val(lamp);
    const float rr = lam / eps;
    const int tid = threadIdx.x;
    const int lane = tid & 63;
    const int w = tid >> 6;
    const int wm = w & 1, wn = w >> 1;
    const int bid = blockIdx.x;
    const int kh = bid & 1;
    const int i0 = ((bid >> 1) & 31) * 128;
    const int j0 = (bid >> 6) * 64;
    const int quad = lane >> 4;
    const int l15 = lane & 15;
    const int h7 = l15 & 7;

    f32x4 zero = {0.f, 0.f, 0.f, 0.f};
    f32x4 accs[4][2];
#pragma unroll
    for (int mt = 0; mt < 4; ++mt)
#pragma unroll
        for (int nt = 0; nt < 2; ++nt) accs[mt][nt] = zero;

    const int lr = lane >> 3;
    const int lc = ((lane & 7) ^ lr) * 8;

    auto stage = [&](int k0, int b) {
        const ushort* ga = KTb + (size_t)(i0 + w * 32 + lr) * NN + k0 + lc;
        ushort* la = &As[b][(w * 32) * 64];
#pragma unroll
        for (int it = 0; it < 4; ++it)
            gload16(ga + (size_t)it * 8 * NN, la + it * 8 * 64);
        const ushort* gb = aT + (size_t)(j0 + w * 16 + lr) * NN + k0 + lc;
#pragma unroll
        for (int it = 0; it < 2; ++it)
            gload16(gb + (size_t)it * 8 * NN, &Bs[b][(w * 16 + it * 8) * 64]);
    };

    const int kbase = kh * (NN / 2);
    stage(kbase, 0);
    __syncthreads();
    for (int step = 0; step < NN / 128; ++step) {
        const int cur = step & 1;
        if (step < NN / 128 - 1) stage(kbase + (step + 1) * 64, cur ^ 1);
#pragma unroll
        for (int ks = 0; ks < 2; ++ks) {
            const int ch = ((ks * 4 + quad) ^ h7) * 8;
            short8 af[4];
#pragma unroll
            for (int mt = 0; mt < 4; ++mt)
                af[mt] = *(const short8*)&As[cur][(wm * 64 + mt * 16 + l15) * 64 + ch];
            short8 bv[2];
#pragma unroll
            for (int nt = 0; nt < 2; ++nt)
                bv[nt] = *(const short8*)&Bs[cur][(wn * 32 + nt * 16 + l15) * 64 + ch];
#pragma unroll
            for (int mt = 0; mt < 4; ++mt)
#pragma unroll
                for (int nt = 0; nt < 2; ++nt)
                    accs[mt][nt] = __builtin_amdgcn_mfma_f32_16x16x32_bf16(
                        af[mt], bv[nt], accs[mt][nt], 0, 0, 0);
        }
        __syncthreads();
    }

    double klp = 0.0;
#pragma unroll
    for (int mt = 0; mt < 4; ++mt)
#pragma unroll
        for (int nt = 0; nt < 2; ++nt) {
            const int ib = i0 + wm * 64 + mt * 16 + quad * 4;
            const int j = j0 + wn * 32 + nt * 16 + l15;
#pragma unroll
            for (int r = 0; r < 4; ++r) {
                float s = accs[mt][nt][r];
                float u = U[(size_t)(ib + r) * BB + j];
                float L = __logf(lam / (lam - u));
                float fv = __expf(rr * L);
                klp -= (double)(fv * (1.0f + L) * s);
            }
        }

    klp = wave_sum(klp);
    if (lane == 0) atomicAdd(&acc[3], klp);
}

__global__ void k_final(const double* __restrict__ acc, const void* epsp,
                        const void* lamp, float* __restrict__ out) {
    float eps = scal_val(epsp), lam = scal_val(lamp);
    double v = (double)eps * (acc[0] + acc[1] - acc[2]) + (double)lam * acc[3];
    out[0] = (float)v;
}

extern "C" void kernel_launch(void* const* d_in, const int* in_sizes, int n_in,
                              void* d_out, int out_size, void* d_ws, size_t ws_size,
                              hipStream_t stream) {
    const float* U = (const float*)d_in[0];
    const float* P = (const float*)d_in[1];
    const float* K = (const float*)d_in[2];
    const void* epsp = d_in[3];
    const void* lamp = d_in[4];

    // ws: acc 256B | Kb 32M | KTb 32M | fT 4M | gT 4M | aT 4M | Y1p 16M | Y2p 16M
    double* acc = (double*)d_ws;
    char* base = (char*)d_ws + 256;
    ushort* Kb  = (ushort*)base;
    ushort* KTb = (ushort*)(base + ((size_t)32 << 20));
    ushort* fT  = (ushort*)(base + ((size_t)64 << 20));
    ushort* gT  = (ushort*)(base + ((size_t)68 << 20));
    ushort* aT  = (ushort*)(base + ((size_t)72 << 20));
    float*  Y1p = (float*)(base + ((size_t)76 << 20));
    float*  Y2p = (float*)(base + ((size_t)92 << 20));

    hipMemsetAsync(acc, 0, 4 * sizeof(double), stream);

    k_prep_K<<<dim3(64, 64), 256, 0, stream>>>(K, Kb, KTb);
    k_prep_fg<<<dim3(8, 64), 256, 0, stream>>>(U, fT, gT, epsp, lamp);
    k_gemm1<<<512, 256, 0, stream>>>(Kb, fT, gT, Y1p, Y2p);
    k_epi<<<dim3(8, 64), 256, 0, stream>>>(Y1p, Y2p, P, aT, acc);
    k_gemm2<<<512, 256, 0, stream>>>(KTb, aT, U, epsp, lamp, acc);
    k_final<<<1, 1, 0, stream>>>(acc, epsp, lamp, (float*)d_out);
}

// Round 4
// 225.404 us; speedup vs baseline: 3.4793x; 1.4146x over previous
//
#include <hip/hip_runtime.h>
#include <hip/hip_bf16.h>

#define NN 4096
#define BB 512

typedef __attribute__((ext_vector_type(8))) short short8;   // 8 bf16 (4 VGPRs)
typedef __attribute__((ext_vector_type(4))) float f32x4;    // MFMA C/D frag
typedef unsigned short ushort;
typedef __attribute__((ext_vector_type(4))) ushort ushort4v;

__device__ __forceinline__ float scal_val(const void* p) {
    int b = *(const int*)p;
    if (b >= 1 && b <= 1000000) return (float)b;
    return __int_as_float(b);
}

// f32 -> bf16 bits, round-to-nearest-even (inputs are finite positive here)
__device__ __forceinline__ ushort f2bf(float x) {
    unsigned u = __float_as_uint(x);
    u += 0x7fffu + ((u >> 16) & 1u);
    return (ushort)(u >> 16);
}

__device__ __forceinline__ void gload16(const void* g, void* l) {
    __builtin_amdgcn_global_load_lds(
        (const __attribute__((address_space(1))) unsigned int*)g,
        (__attribute__((address_space(3))) unsigned int*)l, 16, 0, 0);
}

__device__ __forceinline__ double wave_sum(double v) {
#pragma unroll
    for (int s = 32; s > 0; s >>= 1) v += __shfl_down(v, s, 64);
    return v;
}

// Partials layout in ws (doubles): [0,512) t1 | [512,1024) t2 | [1024,1536) t3
// | [1536,2048) kl.  Every slot is written every call (no memset needed).

// ---------------------------------------------------------------------------
// K (fp32 NxN) -> Kb (bf16, row-major) and KTb (bf16, transposed row-major)
// ---------------------------------------------------------------------------
__global__ __launch_bounds__(256) void k_prep_K(const float* __restrict__ K,
                                                ushort* __restrict__ Kb,
                                                ushort* __restrict__ KTb) {
    __shared__ float tile[64][65];
    const int t = threadIdx.x;
    const int tx = t & 15, ty = t >> 4;
    const int c0 = blockIdx.x * 64, r0 = blockIdx.y * 64;
#pragma unroll
    for (int it = 0; it < 4; ++it) {
        int row = ty + it * 16;
        float4 v = *(const float4*)&K[(size_t)(r0 + row) * NN + c0 + tx * 4];
        ushort4v o = {f2bf(v.x), f2bf(v.y), f2bf(v.z), f2bf(v.w)};
        *(ushort4v*)&Kb[(size_t)(r0 + row) * NN + c0 + tx * 4] = o;
        tile[row][tx * 4 + 0] = v.x;
        tile[row][tx * 4 + 1] = v.y;
        tile[row][tx * 4 + 2] = v.z;
        tile[row][tx * 4 + 3] = v.w;
    }
    __syncthreads();
#pragma unroll
    for (int it = 0; it < 4; ++it) {
        int row = ty + it * 16;  // col within tile -> KT row (c0+row)
        ushort4v o = {f2bf(tile[tx * 4 + 0][row]), f2bf(tile[tx * 4 + 1][row]),
                      f2bf(tile[tx * 4 + 2][row]), f2bf(tile[tx * 4 + 3][row])};
        *(ushort4v*)&KTb[(size_t)(c0 + row) * NN + r0 + tx * 4] = o;
    }
}

// ---------------------------------------------------------------------------
// U (fp32 NxB) -> fT, gT (bf16, TRANSPOSED: [j][k] row-major, BxN)
// ---------------------------------------------------------------------------
__global__ __launch_bounds__(256) void k_prep_fg(const float* __restrict__ U,
                                                 ushort* __restrict__ fT,
                                                 ushort* __restrict__ gT,
                                                 const void* epsp, const void* lamp) {
    __shared__ float tf[64][65];
    __shared__ float tg[64][65];
    const float eps = scal_val(epsp), lam = scal_val(lamp);
    const float rr = lam / eps;
    const int t = threadIdx.x;
    const int tx = t & 15, ty = t >> 4;
    const int c0 = blockIdx.x * 64;  // U col tile (j)
    const int r0 = blockIdx.y * 64;  // U row tile (k)
#pragma unroll
    for (int it = 0; it < 4; ++it) {
        int row = ty + it * 16;
        float4 v = *(const float4*)&U[(size_t)(r0 + row) * BB + c0 + tx * 4];
        float uu[4] = {v.x, v.y, v.z, v.w};
#pragma unroll
        for (int k = 0; k < 4; ++k) {
            float L = __logf(lam / (lam - uu[k]));
            float fl = rr * L;
            float fv = __expf(fl);
            tf[row][tx * 4 + k] = fv;
            tg[row][tx * 4 + k] = fv * fl;
        }
    }
    __syncthreads();
#pragma unroll
    for (int it = 0; it < 4; ++it) {
        int row = ty + it * 16;
        ushort4v of = {f2bf(tf[tx * 4 + 0][row]), f2bf(tf[tx * 4 + 1][row]),
                       f2bf(tf[tx * 4 + 2][row]), f2bf(tf[tx * 4 + 3][row])};
        ushort4v og = {f2bf(tg[tx * 4 + 0][row]), f2bf(tg[tx * 4 + 1][row]),
                       f2bf(tg[tx * 4 + 2][row]), f2bf(tg[tx * 4 + 3][row])};
        *(ushort4v*)&fT[(size_t)(c0 + row) * NN + r0 + tx * 4] = of;
        *(ushort4v*)&gT[(size_t)(c0 + row) * NN + r0 + tx * 4] = og;
    }
}

// ---------------------------------------------------------------------------
// GEMM1 (MFMA, dual, K-split 2): partial Y1 = Kb@f, Y2 = Kb@g over K-half.
// Tile 128(M)x64(j), BK=64, dbuf, XOR-swizzled LDS.  Grid 512 (2 blocks/CU).
// ---------------------------------------------------------------------------
__global__ __launch_bounds__(256) void k_gemm1(const ushort* __restrict__ Kb,
                                               const ushort* __restrict__ fT,
                                               const ushort* __restrict__ gT,
                                               float* __restrict__ Y1p,
                                               float* __restrict__ Y2p) {
    __shared__ __align__(16) ushort As[2][128 * 64];
    __shared__ __align__(16) ushort Bf[2][64 * 64];
    __shared__ __align__(16) ushort Bg[2][64 * 64];

    const int tid = threadIdx.x;
    const int lane = tid & 63;
    const int w = tid >> 6;
    const int wm = w & 1, wn = w >> 1;
    const int bid = blockIdx.x;
    const int kh = bid & 1;                  // K-half
    const int i0 = ((bid >> 1) & 31) * 128;  // M panel
    const int j0 = (bid >> 6) * 64;          // j panel
    const int quad = lane >> 4;
    const int l15 = lane & 15;
    const int h7 = l15 & 7;

    f32x4 zero = {0.f, 0.f, 0.f, 0.f};
    f32x4 accf[4][2], accg[4][2];
#pragma unroll
    for (int mt = 0; mt < 4; ++mt)
#pragma unroll
        for (int nt = 0; nt < 2; ++nt) { accf[mt][nt] = zero; accg[mt][nt] = zero; }

    const int lr = lane >> 3;                 // 0..7 row-within-slab
    const int lc = ((lane & 7) ^ lr) * 8;     // XOR-swizzled fetch chunk

    auto stage = [&](int k0, int b) {
        const ushort* ga = Kb + (size_t)(i0 + w * 32 + lr) * NN + k0 + lc;
        ushort* la = &As[b][(w * 32) * 64];
#pragma unroll
        for (int it = 0; it < 4; ++it)
            gload16(ga + (size_t)it * 8 * NN, la + it * 8 * 64);
        const ushort* gf = fT + (size_t)(j0 + w * 16 + lr) * NN + k0 + lc;
        const ushort* gg = gT + (size_t)(j0 + w * 16 + lr) * NN + k0 + lc;
#pragma unroll
        for (int it = 0; it < 2; ++it) {
            gload16(gf + (size_t)it * 8 * NN, &Bf[b][(w * 16 + it * 8) * 64]);
            gload16(gg + (size_t)it * 8 * NN, &Bg[b][(w * 16 + it * 8) * 64]);
        }
    };

    const int kbase = kh * (NN / 2);
    stage(kbase, 0);
    __syncthreads();
    for (int step = 0; step < NN / 128; ++step) {   // 32 steps of BK=64
        const int cur = step & 1;
        if (step < NN / 128 - 1) stage(kbase + (step + 1) * 64, cur ^ 1);
#pragma unroll
        for (int ks = 0; ks < 2; ++ks) {
            const int ch = ((ks * 4 + quad) ^ h7) * 8;   // swizzled read chunk
            short8 af[4];
#pragma unroll
            for (int mt = 0; mt < 4; ++mt)
                af[mt] = *(const short8*)&As[cur][(wm * 64 + mt * 16 + l15) * 64 + ch];
            short8 bfv[2], bgv[2];
#pragma unroll
            for (int nt = 0; nt < 2; ++nt) {
                bfv[nt] = *(const short8*)&Bf[cur][(wn * 32 + nt * 16 + l15) * 64 + ch];
                bgv[nt] = *(const short8*)&Bg[cur][(wn * 32 + nt * 16 + l15) * 64 + ch];
            }
#pragma unroll
            for (int mt = 0; mt < 4; ++mt)
#pragma unroll
                for (int nt = 0; nt < 2; ++nt) {
                    accf[mt][nt] = __builtin_amdgcn_mfma_f32_16x16x32_bf16(
                        af[mt], bfv[nt], accf[mt][nt], 0, 0, 0);
                    accg[mt][nt] = __builtin_amdgcn_mfma_f32_16x16x32_bf16(
                        af[mt], bgv[nt], accg[mt][nt], 0, 0, 0);
                }
        }
        __syncthreads();
    }

    // Store fp32 partials [kh][i][j].  C/D layout: col=lane&15, row=quad*4+reg.
    float* o1 = Y1p + (size_t)kh * NN * BB;
    float* o2 = Y2p + (size_t)kh * NN * BB;
#pragma unroll
    for (int mt = 0; mt < 4; ++mt)
#pragma unroll
        for (int nt = 0; nt < 2; ++nt) {
            const int ib = i0 + wm * 64 + mt * 16 + quad * 4;
            const int j = j0 + wn * 32 + nt * 16 + l15;
#pragma unroll
            for (int r = 0; r < 4; ++r) {
                o1[(size_t)(ib + r) * BB + j] = accf[mt][nt][r];
                o2[(size_t)(ib + r) * BB + j] = accg[mt][nt][r];
            }
        }
}

// ---------------------------------------------------------------------------
// Epilogue: Y = sum of halves; a = P/Y1; t1 += a*Y2, t2 += P*log(a), t3 += P;
// aT (bf16, [j][i]) via LDS transpose.  Per-block partials (NO atomics).
// ---------------------------------------------------------------------------
__global__ __launch_bounds__(256) void k_epi(const float* __restrict__ Y1p,
                                             const float* __restrict__ Y2p,
                                             const float* __restrict__ P,
                                             ushort* __restrict__ aT,
                                             double* __restrict__ parts) {
    __shared__ float ta[64][65];
    __shared__ double bred[4][3];
    const int t = threadIdx.x;
    const int lane = t & 63;
    const int w = t >> 6;
    const int tx = t & 15, ty = t >> 4;
    const int j0 = blockIdx.x * 64;
    const int i0 = blockIdx.y * 64;
    const int bid = blockIdx.y * 8 + blockIdx.x;
    const size_t H = (size_t)NN * BB;

    double t1 = 0.0, t2 = 0.0, t3 = 0.0;
#pragma unroll
    for (int it = 0; it < 4; ++it) {
        int row = ty + it * 16;
        size_t off = (size_t)(i0 + row) * BB + j0 + tx * 4;
        float4 a1 = *(const float4*)(Y1p + off);
        float4 b1 = *(const float4*)(Y1p + H + off);
        float4 a2 = *(const float4*)(Y2p + off);
        float4 b2 = *(const float4*)(Y2p + H + off);
        float4 p4 = *(const float4*)(P + off);
        float y1[4] = {a1.x + b1.x, a1.y + b1.y, a1.z + b1.z, a1.w + b1.w};
        float y2[4] = {a2.x + b2.x, a2.y + b2.y, a2.z + b2.z, a2.w + b2.w};
        float pv[4] = {p4.x, p4.y, p4.z, p4.w};
#pragma unroll
        for (int e = 0; e < 4; ++e) {
            float aij = pv[e] / y1[e];
            t1 += (double)(aij * y2[e]);
            t2 += (double)(pv[e] * __logf(aij));
            t3 += (double)pv[e];
            ta[row][tx * 4 + e] = aij;
        }
    }
    __syncthreads();
#pragma unroll
    for (int it = 0; it < 4; ++it) {
        int row = ty + it * 16;  // col within tile -> aT row (j0+row)
        ushort4v o = {f2bf(ta[tx * 4 + 0][row]), f2bf(ta[tx * 4 + 1][row]),
                      f2bf(ta[tx * 4 + 2][row]), f2bf(ta[tx * 4 + 3][row])};
        *(ushort4v*)&aT[(size_t)(j0 + row) * NN + i0 + tx * 4] = o;
    }

    t1 = wave_sum(t1); t2 = wave_sum(t2); t3 = wave_sum(t3);
    if (lane == 0) { bred[w][0] = t1; bred[w][1] = t2; bred[w][2] = t3; }
    __syncthreads();
    if (t == 0) {
        double a = 0, b = 0, c = 0;
#pragma unroll
        for (int ww = 0; ww < 4; ++ww) { a += bred[ww][0]; b += bred[ww][1]; c += bred[ww][2]; }
        parts[bid] = a;
        parts[512 + bid] = b;
        parts[1024 + bid] = c;
    }
}

// ---------------------------------------------------------------------------
// GEMM2 (MFMA, K-split 2): partial S = KTb @ a; kl -= f*(1+L)*S  (linear in S,
// each block writes its partial kl to its own slot — NO atomics).
// ---------------------------------------------------------------------------
__global__ __launch_bounds__(256) void k_gemm2(const ushort* __restrict__ KTb,
                                               const ushort* __restrict__ aT,
                                               const float* __restrict__ U,
                                               const void* epsp, const void* lamp,
                                               double* __restrict__ parts) {
    __shared__ __align__(16) ushort As[2][128 * 64];
    __shared__ __align__(16) ushort Bs[2][64 * 64];
    __shared__ double bred[4];

    const float eps = scal_val(epsp), lam = scal_val(lamp);
    const float rr = lam / eps;
    const int tid = threadIdx.x;
    const int lane = tid & 63;
    const int w = tid >> 6;
    const int wm = w & 1, wn = w >> 1;
    const int bid = blockIdx.x;
    const int kh = bid & 1;
    const int i0 = ((bid >> 1) & 31) * 128;
    const int j0 = (bid >> 6) * 64;
    const int quad = lane >> 4;
    const int l15 = lane & 15;
    const int h7 = l15 & 7;

    f32x4 zero = {0.f, 0.f, 0.f, 0.f};
    f32x4 accs[4][2];
#pragma unroll
    for (int mt = 0; mt < 4; ++mt)
#pragma unroll
        for (int nt = 0; nt < 2; ++nt) accs[mt][nt] = zero;

    const int lr = lane >> 3;
    const int lc = ((lane & 7) ^ lr) * 8;

    auto stage = [&](int k0, int b) {
        const ushort* ga = KTb + (size_t)(i0 + w * 32 + lr) * NN + k0 + lc;
        ushort* la = &As[b][(w * 32) * 64];
#pragma unroll
        for (int it = 0; it < 4; ++it)
            gload16(ga + (size_t)it * 8 * NN, la + it * 8 * 64);
        const ushort* gb = aT + (size_t)(j0 + w * 16 + lr) * NN + k0 + lc;
#pragma unroll
        for (int it = 0; it < 2; ++it)
            gload16(gb + (size_t)it * 8 * NN, &Bs[b][(w * 16 + it * 8) * 64]);
    };

    const int kbase = kh * (NN / 2);
    stage(kbase, 0);
    __syncthreads();
    for (int step = 0; step < NN / 128; ++step) {
        const int cur = step & 1;
        if (step < NN / 128 - 1) stage(kbase + (step + 1) * 64, cur ^ 1);
#pragma unroll
        for (int ks = 0; ks < 2; ++ks) {
            const int ch = ((ks * 4 + quad) ^ h7) * 8;
            short8 af[4];
#pragma unroll
            for (int mt = 0; mt < 4; ++mt)
                af[mt] = *(const short8*)&As[cur][(wm * 64 + mt * 16 + l15) * 64 + ch];
            short8 bv[2];
#pragma unroll
            for (int nt = 0; nt < 2; ++nt)
                bv[nt] = *(const short8*)&Bs[cur][(wn * 32 + nt * 16 + l15) * 64 + ch];
#pragma unroll
            for (int mt = 0; mt < 4; ++mt)
#pragma unroll
                for (int nt = 0; nt < 2; ++nt)
                    accs[mt][nt] = __builtin_amdgcn_mfma_f32_16x16x32_bf16(
                        af[mt], bv[nt], accs[mt][nt], 0, 0, 0);
        }
        __syncthreads();
    }

    double klp = 0.0;
#pragma unroll
    for (int mt = 0; mt < 4; ++mt)
#pragma unroll
        for (int nt = 0; nt < 2; ++nt) {
            const int ib = i0 + wm * 64 + mt * 16 + quad * 4;
            const int j = j0 + wn * 32 + nt * 16 + l15;
#pragma unroll
            for (int r = 0; r < 4; ++r) {
                float s = accs[mt][nt][r];
                float u = U[(size_t)(ib + r) * BB + j];
                float L = __logf(lam / (lam - u));
                float fv = __expf(rr * L);
                klp -= (double)(fv * (1.0f + L) * s);
            }
        }

    klp = wave_sum(klp);
    if (lane == 0) bred[w] = klp;
    __syncthreads();
    if (tid == 0) {
        double s = bred[0] + bred[1] + bred[2] + bred[3];
        parts[1536 + bid] = s;
    }
}

// ---------------------------------------------------------------------------
// Final: sum 4x512 partials, out = eps*(t1+t2-t3) + lam*kl
// ---------------------------------------------------------------------------
__global__ __launch_bounds__(256) void k_final(const double* __restrict__ parts,
                                               const void* epsp, const void* lamp,
                                               float* __restrict__ out) {
    __shared__ double red[4][4];
    const int tid = threadIdx.x;
    const int lane = tid & 63, w = tid >> 6;
    double s[4] = {0.0, 0.0, 0.0, 0.0};
#pragma unroll
    for (int v = 0; v < 4; ++v)
        for (int i = tid; i < 512; i += 256) s[v] += parts[v * 512 + i];
#pragma unroll
    for (int v = 0; v < 4; ++v) s[v] = wave_sum(s[v]);
    if (lane == 0) {
#pragma unroll
        for (int v = 0; v < 4; ++v) red[w][v] = s[v];
    }
    __syncthreads();
    if (tid == 0) {
        double t1 = 0, t2 = 0, t3 = 0, kl = 0;
#pragma unroll
        for (int ww = 0; ww < 4; ++ww) {
            t1 += red[ww][0]; t2 += red[ww][1]; t3 += red[ww][2]; kl += red[ww][3];
        }
        float eps = scal_val(epsp), lam = scal_val(lamp);
        out[0] = (float)((double)eps * (t1 + t2 - t3) + (double)lam * kl);
    }
}

extern "C" void kernel_launch(void* const* d_in, const int* in_sizes, int n_in,
                              void* d_out, int out_size, void* d_ws, size_t ws_size,
                              hipStream_t stream) {
    const float* U = (const float*)d_in[0];
    const float* P = (const float*)d_in[1];
    const float* K = (const float*)d_in[2];
    const void* epsp = d_in[3];
    const void* lamp = d_in[4];

    // ws: parts 16KB (pad to 64KB) | Kb 32M | KTb 32M | fT 4M | gT 4M | aT 4M
    //     | Y1p 16M | Y2p 16M
    double* parts = (double*)d_ws;
    char* base = (char*)d_ws + (64 << 10);
    ushort* Kb  = (ushort*)base;
    ushort* KTb = (ushort*)(base + ((size_t)32 << 20));
    ushort* fT  = (ushort*)(base + ((size_t)64 << 20));
    ushort* gT  = (ushort*)(base + ((size_t)68 << 20));
    ushort* aT  = (ushort*)(base + ((size_t)72 << 20));
    float*  Y1p = (float*)(base + ((size_t)76 << 20));
    float*  Y2p = (float*)(base + ((size_t)92 << 20));

    k_prep_K<<<dim3(64, 64), 256, 0, stream>>>(K, Kb, KTb);
    k_prep_fg<<<dim3(8, 64), 256, 0, stream>>>(U, fT, gT, epsp, lamp);
    k_gemm1<<<512, 256, 0, stream>>>(Kb, fT, gT, Y1p, Y2p);
    k_epi<<<dim3(8, 64), 256, 0, stream>>>(Y1p, Y2p, P, aT, parts);
    k_gemm2<<<512, 256, 0, stream>>>(KTb, aT, U, epsp, lamp, parts);
    k_final<<<1, 256, 0, stream>>>(parts, epsp, lamp, (float*)d_out);
}